// Round 10
// baseline (740.489 us; speedup 1.0000x reference)
//
#include <hip/hip_runtime.h>
#include <cstdint>

#define KT 9408      // K_TOTAL
#define NBLK 512     // fused hypernet grid size (2 blocks/CU guaranteed resident)

// ---------------------------------------------------------------------------
// bf16 helpers
// ---------------------------------------------------------------------------
typedef __attribute__((ext_vector_type(8))) short bf16x8;
typedef __attribute__((ext_vector_type(4))) float f32x4;

__device__ inline uint32_t pkbf(float lo, float hi) {   // 2 f32 -> packed bf16x2 (RNE)
    uint32_t a = __builtin_bit_cast(uint32_t, lo);
    uint32_t b = __builtin_bit_cast(uint32_t, hi);
    a = (a + 0x7FFFu + ((a >> 16) & 1u)) >> 16;
    b = (b + 0x7FFFu + ((b >> 16) & 1u)) & 0xFFFF0000u;
    return a | b;
}
__device__ inline uint32_t pk_hi(float a, float b, float& ra, float& rb) {
    uint32_t ua = __builtin_bit_cast(uint32_t, a);
    uint32_t ub = __builtin_bit_cast(uint32_t, b);
    uint32_t ha = (ua + 0x7FFFu + ((ua >> 16) & 1u)) & 0xFFFF0000u;
    uint32_t hb = (ub + 0x7FFFu + ((ub >> 16) & 1u)) & 0xFFFF0000u;
    ra = a - __builtin_bit_cast(float, ha);
    rb = b - __builtin_bit_cast(float, hb);
    return (ha >> 16) | hb;
}

#define MFMA16(a, b, c) __builtin_amdgcn_mfma_f32_16x16x32_bf16(a, b, c, 0, 0, 0)

// ---------------------------------------------------------------------------
// Device-scope global barrier (monotone counter, zeroed per launch by memset).
// Barrier g passes when cnt reaches g*NBLK. __threadfence gives agent-scope
// release/acquire (writeback+invalidate) around the arrival — the standard
// grid-sync pattern; atomicAdd on global is device-scope by default [m20].
// ---------------------------------------------------------------------------
__device__ inline void gbar(int* cnt, int target) {
    __syncthreads();
    if (threadIdx.x == 0) {
        __threadfence();
        __hip_atomic_fetch_add(cnt, 1, __ATOMIC_ACQ_REL, __HIP_MEMORY_SCOPE_AGENT);
        while (__hip_atomic_load(cnt, __ATOMIC_ACQUIRE, __HIP_MEMORY_SCOPE_AGENT) < target)
            __builtin_amdgcn_s_sleep(8);
        __threadfence();
    }
    __syncthreads();
}

// ---------------------------------------------------------------------------
// Small-layer stage: Y[b][o] = bias1[o](+bias2[o]) + sum_k X[b,k]W[o,k], opt
// ReLU. Cells = 32*O spread exactly over NBLK blocks; TPC threads slice K per
// cell (interleaved float4s -> each cell's TPC threads read 128B contiguous
// W per iteration). LDS combine + epilogue by j==0 threads.
// ---------------------------------------------------------------------------
template <int TPC>
__device__ void small_stage(const float* __restrict__ X1, const float* __restrict__ W1, int K1,
                            const float* __restrict__ X2, const float* __restrict__ W2, int K2,
                            const float* __restrict__ bias1, const float* __restrict__ bias2,
                            float* __restrict__ Y, int O, bool relu,
                            int blk, int t, float* red)
{
    constexpr int CPB = 256 / TPC;
    const int cl = t / TPC, j = t % TPC;
    const int c  = blk * CPB + cl;        // 0 .. 32*O-1 (exact tiling)
    const int o  = c >> 5, b = c & 31;
    const int K  = K1 + K2;
    const int iters = K / (TPC * 4);

    float acc = 0.f;
#pragma unroll 4
    for (int it = 0; it < iters; ++it) {
        int kg = it * TPC * 4 + j * 4;
        const float *xp, *wp;
        if (kg < K1) { xp = X1 + (size_t)b * K1 + kg;        wp = W1 + (size_t)o * K1 + kg; }
        else         { xp = X2 + (size_t)b * K2 + (kg - K1); wp = W2 + (size_t)o * K2 + (kg - K1); }
        float4 xv = *(const float4*)xp;
        float4 wv = *(const float4*)wp;
        acc += xv.x * wv.x + xv.y * wv.y + xv.z * wv.z + xv.w * wv.w;
    }
    red[t] = acc;
    __syncthreads();
    if (j == 0) {
        float s = bias1[o] + (bias2 ? bias2[o] : 0.f);
#pragma unroll
        for (int q = 0; q < TPC; ++q) s += red[cl * TPC + q];
        Y[(size_t)b * O + o] = relu ? fmaxf(s, 0.f) : s;
    }
    __syncthreads();
}

// ---------------------------------------------------------------------------
// MFMA partial-GEMM unit (R9-proven fragment convention). Unit u covers
// o-tile (u%147)*64 and k-split s = u/147. partial[s][b][o].
// ---------------------------------------------------------------------------
__device__ void mfma_unit(int u, const float* __restrict__ X1, const float* __restrict__ W1, int K1,
                          const float* __restrict__ X2, const float* __restrict__ W2, int K2,
                          float* __restrict__ partial, int O, int ksplit, int t)
{
    const int l  = t & 63;
    const int g  = l >> 4;
    const int n  = l & 15;
    const int o0 = (u % 147) * 64 + (t >> 6) * 16;
    const int s  = u / 147;
    const int kchunk = (K1 + K2) / ksplit;
    const int kbeg   = s * kchunk;
    const int kend   = kbeg + kchunk;

    f32x4 accA, accB;
#pragma unroll
    for (int r = 0; r < 4; ++r) { accA[r] = 0.f; accB[r] = 0.f; }

#pragma unroll 2
    for (int kc = kbeg; kc < kend; kc += 32) {
        const float* Wr;  const float* Xb;  int kk; int ld;
        if (kc < K1) { Wr = W1; Xb = X1; kk = kc;      ld = K1; }
        else         { Wr = W2; Xb = X2; kk = kc - K1; ld = K2; }

        const float* wp = Wr + (size_t)(o0 + n) * ld + kk + 4 * g;
        float4 wlo = *(const float4*)wp;
        float4 whi = *(const float4*)(wp + 16);
        union { bf16x8 v; uint32_t u4[4]; } wf;
        wf.u4[0] = pkbf(wlo.x, wlo.y); wf.u4[1] = pkbf(wlo.z, wlo.w);
        wf.u4[2] = pkbf(whi.x, whi.y); wf.u4[3] = pkbf(whi.z, whi.w);

#pragma unroll
        for (int bh = 0; bh < 2; ++bh) {
            const float* xp = Xb + (size_t)(16 * bh + n) * ld + kk + 4 * g;
            float4 xa = *(const float4*)xp;
            float4 xb = *(const float4*)(xp + 16);
            float r0, r1, r2, r3, r4, r5, r6, r7;
            union { bf16x8 v; uint32_t u4[4]; } xh, xl;
            xh.u4[0] = pk_hi(xa.x, xa.y, r0, r1);
            xh.u4[1] = pk_hi(xa.z, xa.w, r2, r3);
            xh.u4[2] = pk_hi(xb.x, xb.y, r4, r5);
            xh.u4[3] = pk_hi(xb.z, xb.w, r6, r7);
            xl.u4[0] = pkbf(r0, r1); xl.u4[1] = pkbf(r2, r3);
            xl.u4[2] = pkbf(r4, r5); xl.u4[3] = pkbf(r6, r7);
            if (bh == 0) {
                accA = MFMA16(xh.v, wf.v, accA);
                accA = MFMA16(xl.v, wf.v, accA);
            } else {
                accB = MFMA16(xh.v, wf.v, accB);
                accB = MFMA16(xl.v, wf.v, accB);
            }
        }
    }

#pragma unroll
    for (int r = 0; r < 4; ++r) {
        partial[((size_t)s * 32 + (4 * g + r)) * O + o0 + n]      = accA[r];
        partial[((size_t)s * 32 + (16 + 4 * g + r)) * O + o0 + n] = accB[r];
    }
}

// ---------------------------------------------------------------------------
// Partial reduce + bias(es): grid-strided over 32*O cells.
// ---------------------------------------------------------------------------
__device__ void reduce_stage(const float* __restrict__ partial,
                             const float* __restrict__ bias1, const float* __restrict__ bias2,
                             float* __restrict__ Y, int O, int ksplit, int blk, int t)
{
    for (int i = blk * 256 + t; i < 32 * O; i += NBLK * 256) {
        int b = i / O, o = i - b * O;
        float s = bias1[o] + (bias2 ? bias2[o] : 0.f);
        for (int k = 0; k < ksplit; ++k)
            s += partial[((size_t)k * 32 + b) * O + o];
        Y[i] = s;
    }
}

// ---------------------------------------------------------------------------
// Fused hypernet: whole chain in one kernel, 7 global barriers.
// ---------------------------------------------------------------------------
__global__ __launch_bounds__(256, 2) void hyper_fused(
    const float* __restrict__ lat,
    const float* __restrict__ w0,  const float* __restrict__ b0,
    const float* __restrict__ w1a, const float* __restrict__ b1a,
    const float* __restrict__ w1b, const float* __restrict__ b1b,
    const float* __restrict__ w1s, const float* __restrict__ b1s,
    const float* __restrict__ w2a, const float* __restrict__ b2a,
    const float* __restrict__ w2b, const float* __restrict__ b2b,
    const float* __restrict__ w2s, const float* __restrict__ b2s,
    const float* __restrict__ wfa, const float* __restrict__ bfa,
    float* __restrict__ h0, float* __restrict__ t1, float* __restrict__ h1,
    float* __restrict__ t2, float* __restrict__ h2, float* __restrict__ ksb,
    float* __restrict__ pbuf, int* __restrict__ cnt)
{
    __shared__ float red[256];
    const int blk = blockIdx.x, t = threadIdx.x;

    // S1: h0 = lat @ w0.T + b0
    small_stage<8>(lat, w0, 512, nullptr, nullptr, 0, b0, nullptr, h0, 512, false, blk, t, red);
    gbar(cnt, 1 * NBLK);
    // S2: t1 = relu(h0 @ w1a.T + b1a)
    small_stage<4>(h0, w1a, 512, nullptr, nullptr, 0, b1a, nullptr, t1, 1024, true, blk, t, red);
    gbar(cnt, 2 * NBLK);
    // S3: h1 = h0 @ w1s.T + b1s + t1 @ w1b.T + b1b
    small_stage<8>(h0, w1s, 512, t1, w1b, 1024, b1s, b1b, h1, 512, false, blk, t, red);
    gbar(cnt, 3 * NBLK);
    // S4: t2 = relu(h1 @ w2a.T + b2a)
    small_stage<4>(h1, w2a, 512, nullptr, nullptr, 0, b2a, nullptr, t2, 1024, true, blk, t, red);
    gbar(cnt, 4 * NBLK);
    // S5: w2 partials (147 o-tiles x 6 k-splits)
    for (int u = blk; u < 147 * 6; u += NBLK)
        mfma_unit(u, h1, w2s, 512, t2, w2b, 1024, pbuf, KT, 6, t);
    gbar(cnt, 5 * NBLK);
    // S6: h2 = reduce + b2s + b2b
    reduce_stage(pbuf, b2s, b2b, h2, KT, 6, blk, t);
    gbar(cnt, 6 * NBLK);
    // S7: wfa partials (147 x 7)
    for (int u = blk; u < 147 * 7; u += NBLK)
        mfma_unit(u, h2, wfa, KT, nullptr, nullptr, 0, pbuf, KT, 7, t);
    gbar(cnt, 7 * NBLK);
    // S8: ksb = reduce + bfa
    reduce_stage(pbuf, bfa, nullptr, ksb, KT, 7, blk, t);
}

// ---------------------------------------------------------------------------
// MFMA conv chain (R8/R9 version — unchanged).
// ---------------------------------------------------------------------------
#define TPW 16   // pixel tiles (16 px) per wave

__global__ __launch_bounds__(256, 3) void conv_mfma(
    const float* __restrict__ x, const float* __restrict__ ks,
    float* __restrict__ out)
{
    const int t  = threadIdx.x;
    const int b  = blockIdx.y;
    const int l  = t & 63;
    const int g  = l >> 4;         // lane group 0..3
    const int n  = l & 15;         // col (pixel-in-tile) / A row offset
    const int wid = blockIdx.x * 4 + (t >> 6);   // wave id in sample, 0..63

    const float* __restrict__ kb = ks + (size_t)b * KT;
    const float* __restrict__ xbase = x + (size_t)b * 524288 + (size_t)(4 * g) * 16384 + n;
    float* __restrict__ obase = out + (size_t)b * 524288 + (size_t)(4 * g) * 16384 + n;

    float e[8];
    auto loadx = [&](int px0) {
        const float* p = xbase + px0;
        e[0] = p[0]; e[1] = p[16384]; e[2] = p[2 * 16384]; e[3] = p[3 * 16384];
        const float* q = p + (size_t)16 * 16384;
        e[4] = q[0]; e[5] = q[16384]; e[6] = q[2 * 16384]; e[7] = q[3 * 16384];
    };
    loadx(wid * TPW * 16);

    auto loadA = [&](const float* W, int ldw, int row0, int k0) -> bf16x8 {
        const float* p = W + (size_t)(row0 + n) * ldw + k0 + 4 * g;
        float4 lo = *(const float4*)p;
        float4 hi = *(const float4*)(p + 16);
        union { bf16x8 v; uint32_t u[4]; } r;
        r.u[0] = pkbf(lo.x, lo.y);
        r.u[1] = pkbf(lo.z, lo.w);
        r.u[2] = pkbf(hi.x, hi.y);
        r.u[3] = pkbf(hi.z, hi.w);
        return r.v;
    };
    auto loadBias = [&](int off) -> f32x4 {
        float4 v = *(const float4*)&kb[off + 4 * g];
        f32x4 r; r[0] = v.x; r[1] = v.y; r[2] = v.z; r[3] = v.w;
        return r;
    };

    bf16x8 ain[4], amid[4][2], aout[2][2], ashort[2];
#pragma unroll
    for (int rt = 0; rt < 4; ++rt) ain[rt] = loadA(kb, 32, 16 * rt, 0);
#pragma unroll
    for (int ot = 0; ot < 4; ++ot)
#pragma unroll
        for (int kf = 0; kf < 2; ++kf) amid[ot][kf] = loadA(kb + 2048, 64, 16 * ot, 32 * kf);
#pragma unroll
    for (int ot = 0; ot < 2; ++ot)
#pragma unroll
        for (int kf = 0; kf < 2; ++kf) aout[ot][kf] = loadA(kb + 6144, 64, 16 * ot, 32 * kf);
#pragma unroll
    for (int ot = 0; ot < 2; ++ot) ashort[ot] = loadA(kb + 8192, 32, 16 * ot, 0);

    f32x4 bin[4], bmid[4], bos[2];
#pragma unroll
    for (int rt = 0; rt < 4; ++rt) bin[rt] = loadBias(9216 + 16 * rt);
#pragma unroll
    for (int ot = 0; ot < 4; ++ot) bmid[ot] = loadBias(9280 + 16 * ot);
#pragma unroll
    for (int ot = 0; ot < 2; ++ot) {
        f32x4 a = loadBias(9344 + 16 * ot);   // b_out
        f32x4 c = loadBias(9376 + 16 * ot);   // b_short
#pragma unroll
        for (int r = 0; r < 4; ++r) a[r] += c[r];
        bos[ot] = a;
    }

#pragma unroll 1
    for (int it = 0; it < TPW; ++it) {
        const int px0 = (wid * TPW + it) * 16;

        union { bf16x8 v; uint32_t u[4]; } bx;
        bx.u[0] = pkbf(e[0], e[1]); bx.u[1] = pkbf(e[2], e[3]);
        bx.u[2] = pkbf(e[4], e[5]); bx.u[3] = pkbf(e[6], e[7]);

        if (it + 1 < TPW) loadx(px0 + 16);   // flies under the MFMA chain

        f32x4 h[4];
#pragma unroll
        for (int rt = 0; rt < 4; ++rt) {
            f32x4 acc = MFMA16(ain[rt], bx.v, bin[rt]);
#pragma unroll
            for (int r = 0; r < 4; ++r) acc[r] = fmaxf(acc[r], 0.f);
            h[rt] = acc;
        }
        union { bf16x8 v; uint32_t u[4]; } hb0, hb1;
        hb0.u[0] = pkbf(h[0][0], h[0][1]); hb0.u[1] = pkbf(h[0][2], h[0][3]);
        hb0.u[2] = pkbf(h[1][0], h[1][1]); hb0.u[3] = pkbf(h[1][2], h[1][3]);
        hb1.u[0] = pkbf(h[2][0], h[2][1]); hb1.u[1] = pkbf(h[2][2], h[2][3]);
        hb1.u[2] = pkbf(h[3][0], h[3][1]); hb1.u[3] = pkbf(h[3][2], h[3][3]);

        f32x4 m[4];
#pragma unroll
        for (int ot = 0; ot < 4; ++ot) {
            f32x4 acc = MFMA16(amid[ot][0], hb0.v, bmid[ot]);
            acc = MFMA16(amid[ot][1], hb1.v, acc);
#pragma unroll
            for (int r = 0; r < 4; ++r) acc[r] = fmaxf(acc[r], 0.f);
            m[ot] = acc;
        }
        union { bf16x8 v; uint32_t u[4]; } mb0, mb1;
        mb0.u[0] = pkbf(m[0][0], m[0][1]); mb0.u[1] = pkbf(m[0][2], m[0][3]);
        mb0.u[2] = pkbf(m[1][0], m[1][1]); mb0.u[3] = pkbf(m[1][2], m[1][3]);
        mb1.u[0] = pkbf(m[2][0], m[2][1]); mb1.u[1] = pkbf(m[2][2], m[2][3]);
        mb1.u[2] = pkbf(m[3][0], m[3][1]); mb1.u[3] = pkbf(m[3][2], m[3][3]);

#pragma unroll
        for (int ot = 0; ot < 2; ++ot) {
            f32x4 acc = MFMA16(ashort[ot], bx.v, bos[ot]);
            acc = MFMA16(aout[ot][0], mb0.v, acc);
            acc = MFMA16(aout[ot][1], mb1.v, acc);
            float* po = obase + (size_t)(16 * ot) * 16384 + px0;
            po[0]         = acc[0];
            po[16384]     = acc[1];
            po[2 * 16384] = acc[2];
            po[3 * 16384] = acc[3];
        }
    }
}

// ---------------------------------------------------------------------------
extern "C" void kernel_launch(void* const* d_in, const int* in_sizes, int n_in,
                              void* d_out, int out_size, void* d_ws, size_t ws_size,
                              hipStream_t stream)
{
    const float* x   = (const float*)d_in[0];
    const float* lat = (const float*)d_in[1];
    const float* w0  = (const float*)d_in[2];
    const float* b0  = (const float*)d_in[3];
    const float* w1a = (const float*)d_in[4];
    const float* b1a = (const float*)d_in[5];
    const float* w1b = (const float*)d_in[6];
    const float* b1b = (const float*)d_in[7];
    const float* w1s = (const float*)d_in[8];
    const float* b1s = (const float*)d_in[9];
    const float* w2a = (const float*)d_in[10];
    const float* b2a = (const float*)d_in[11];
    const float* w2b = (const float*)d_in[12];
    const float* b2b = (const float*)d_in[13];
    const float* w2s = (const float*)d_in[14];
    const float* b2s = (const float*)d_in[15];
    const float* wfa = (const float*)d_in[16];
    const float* bfa = (const float*)d_in[17];

    // intermediates in d_ws (~2.8 MB)
    float* ws  = (float*)d_ws;
    float* h0  = ws;               // 32*512
    float* t1  = ws + 16384;       // 32*1024
    float* h1  = ws + 49152;       // 32*512
    float* t2  = ws + 65536;       // 32*1024
    float* h2  = ws + 98304;       // 32*9408
    float* ksb = ws + 399360;      // 32*9408
    // partials in d_out base (8.4 MB); barrier counter at +62 MB; conv
    // overwrites the whole 64 MB at the end.
    float* pbuf = (float*)d_out;
    int*   cnt  = (int*)((char*)d_out + 62u * 1024u * 1024u);

    hipMemsetAsync(cnt, 0, 4, stream);

    hyper_fused<<<dim3(NBLK), dim3(256), 0, stream>>>(
        lat, w0, b0, w1a, b1a, w1b, b1b, w1s, b1s,
        w2a, b2a, w2b, b2b, w2s, b2s, wfa, bfa,
        h0, t1, h1, t2, h2, ksb, pbuf, cnt);

    conv_mfma<<<dim3(16, 32), dim3(256), 0, stream>>>(x, ksb, (float*)d_out);
}

// Round 11
// 295.173 us; speedup vs baseline: 2.5087x; 2.5087x over previous
//
#include <hip/hip_runtime.h>
#include <cstdint>

#define KT 9408      // K_TOTAL
#define NT 256       // o-tile per block
#define KC 16        // k sub-chunk staged in LDS

// ---------------------------------------------------------------------------
// f32 partial GEMM (R5-exact) — used for the four small layers only.
// ---------------------------------------------------------------------------
__global__ __launch_bounds__(256, 1) void gemm32_partial(
    const float* __restrict__ X1, const float* __restrict__ W1, int K1,
    const float* __restrict__ X2, const float* __restrict__ W2, int K2,
    float* __restrict__ partial, int O, int ksplit)
{
    __shared__ float Xs[KC][32];     // [k_local][b]
    __shared__ float Wt[KC][NT];     // [k_local][o_local] transposed

    const int t      = threadIdx.x;
    const int o0     = blockIdx.x * NT;
    const int s      = blockIdx.y;
    const int kchunk = (K1 + K2) / ksplit;     // multiple of KC
    const int kbeg   = s * kchunk;
    const int kend   = kbeg + kchunk;
    const int lane   = t & 63;
    const int wv     = t >> 6;                 // wave id -> b-group (8 b's)

    const int sr  = t >> 2;                    // 0..63  (+64*p)
    const int sc4 = (t & 3) << 2;              // 0,4,8,12

    float4 wpre[4];
    float  xpre[2];

    {
        int kc0 = kbeg;
#pragma unroll
        for (int p = 0; p < 4; ++p) {
            int r = sr + 64 * p;
            int o = o0 + r;
            int kg = kc0 + sc4;
            float4 v = make_float4(0.f, 0.f, 0.f, 0.f);
            if (o < O)
                v = (kg < K1) ? *(const float4*)&W1[(size_t)o * K1 + kg]
                              : *(const float4*)&W2[(size_t)o * K2 + (kg - K1)];
            wpre[p] = v;
        }
#pragma unroll
        for (int it = 0; it < 2; ++it) {
            int idx = t + 256 * it;
            int kg  = kc0 + (idx >> 5);
            int bb  = idx & 31;
            xpre[it] = (kg < K1) ? X1[(size_t)bb * K1 + kg]
                                 : X2[(size_t)bb * K2 + (kg - K1)];
        }
    }

    float acc[8][4];
#pragma unroll
    for (int bi = 0; bi < 8; bi++)
#pragma unroll
        for (int j = 0; j < 4; j++) acc[bi][j] = 0.f;

    for (int kc0 = kbeg; kc0 < kend; kc0 += KC) {
#pragma unroll
        for (int it = 0; it < 2; ++it) {
            int idx = t + 256 * it;
            Xs[idx >> 5][idx & 31] = xpre[it];
        }
#pragma unroll
        for (int p = 0; p < 4; ++p) {
            int r = sr + 64 * p;
            Wt[sc4 + 0][r] = wpre[p].x;
            Wt[sc4 + 1][r] = wpre[p].y;
            Wt[sc4 + 2][r] = wpre[p].z;
            Wt[sc4 + 3][r] = wpre[p].w;
        }
        __syncthreads();

        if (kc0 + KC < kend) {
            int kn = kc0 + KC;
#pragma unroll
            for (int p = 0; p < 4; ++p) {
                int r = sr + 64 * p;
                int o = o0 + r;
                int kg = kn + sc4;
                float4 v = make_float4(0.f, 0.f, 0.f, 0.f);
                if (o < O)
                    v = (kg < K1) ? *(const float4*)&W1[(size_t)o * K1 + kg]
                                  : *(const float4*)&W2[(size_t)o * K2 + (kg - K1)];
                wpre[p] = v;
            }
#pragma unroll
            for (int it = 0; it < 2; ++it) {
                int idx = t + 256 * it;
                int kg  = kn + (idx >> 5);
                int bb  = idx & 31;
                xpre[it] = (kg < K1) ? X1[(size_t)bb * K1 + kg]
                                     : X2[(size_t)bb * K2 + (kg - K1)];
            }
        }

#pragma unroll
        for (int c = 0; c < KC; c++) {
            float4 xa = *(const float4*)&Xs[c][wv * 8];       // wave-broadcast
            float4 xb = *(const float4*)&Xs[c][wv * 8 + 4];
            float xv[8] = {xa.x, xa.y, xa.z, xa.w, xb.x, xb.y, xb.z, xb.w};
            float w[4];
#pragma unroll
            for (int j = 0; j < 4; j++) w[j] = Wt[c][lane + 64 * j];
#pragma unroll
            for (int bi = 0; bi < 8; bi++)
#pragma unroll
                for (int j = 0; j < 4; j++) acc[bi][j] += xv[bi] * w[j];
        }
        __syncthreads();
    }

#pragma unroll
    for (int bi = 0; bi < 8; bi++) {
        int b = wv * 8 + bi;
#pragma unroll
        for (int j = 0; j < 4; j++) {
            int o = o0 + lane + 64 * j;
            if (o < O)
                partial[((size_t)s * 32 + b) * O + o] = acc[bi][j];
        }
    }
}

// ---------------------------------------------------------------------------
__global__ __launch_bounds__(256) void reduce_bias(
    const float* __restrict__ partial, const float* __restrict__ bias1,
    const float* __restrict__ bias2, float* __restrict__ Y, int O, int relu,
    int ksplit)
{
    int idx = blockIdx.x * 256 + threadIdx.x;
    if (idx >= 32 * O) return;
    int b = idx / O, o = idx - b * O;
    float s = bias1[o] + (bias2 ? bias2[o] : 0.f);
    for (int k = 0; k < ksplit; k++)
        s += partial[((size_t)k * 32 + b) * O + o];
    Y[idx] = relu ? fmaxf(s, 0.f) : s;
}

// ---------------------------------------------------------------------------
// bf16 helpers
// ---------------------------------------------------------------------------
typedef __attribute__((ext_vector_type(8))) short bf16x8;
typedef __attribute__((ext_vector_type(4))) float f32x4;

__device__ inline uint32_t pkbf(float lo, float hi) {   // 2 f32 -> packed bf16x2 (RNE)
    uint32_t a = __builtin_bit_cast(uint32_t, lo);
    uint32_t b = __builtin_bit_cast(uint32_t, hi);
    a = (a + 0x7FFFu + ((a >> 16) & 1u)) >> 16;
    b = (b + 0x7FFFu + ((b >> 16) & 1u)) & 0xFFFF0000u;
    return a | b;
}
__device__ inline uint32_t pk_hi(float a, float b, float& ra, float& rb) {
    uint32_t ua = __builtin_bit_cast(uint32_t, a);
    uint32_t ub = __builtin_bit_cast(uint32_t, b);
    uint32_t ha = (ua + 0x7FFFu + ((ua >> 16) & 1u)) & 0xFFFF0000u;
    uint32_t hb = (ub + 0x7FFFu + ((ub >> 16) & 1u)) & 0xFFFF0000u;
    ra = a - __builtin_bit_cast(float, ha);
    rb = b - __builtin_bit_cast(float, hb);
    return (ha >> 16) | hb;
}

#define MFMA16(a, b, c) __builtin_amdgcn_mfma_f32_16x16x32_bf16(a, b, c, 0, 0, 0)

// ---------------------------------------------------------------------------
// MFMA partial GEMM, software-pipelined (R11 change).
// R10's profile exposed the R9 version as latency-bound: VGPR_Count=36 ->
// the compiler serialized the 6 float4 loads per k-chunk. Fix: explicit
// 2-stage double buffer with NAMED register sets (A/B, statically indexed),
// stepping 64 k per iteration so both parities are unrolled. B's loads are
// issued before A is consumed -> >=6 loads always in flight.
// Caller guarantees: kchunk % 64 == 0 and K1 % 64 == 0 (no straddles).
// Fragment convention identical to the verified conv kernel.
// ---------------------------------------------------------------------------
#define GLOAD(SUF, kcv)                                                        \
    {                                                                          \
        int _kc = (kcv);                                                       \
        const float *_Wr, *_Xb; int _kk, _ld;                                  \
        if (_kc < K1) { _Wr = W1; _Xb = X1; _kk = _kc;      _ld = K1; }        \
        else          { _Wr = W2; _Xb = X2; _kk = _kc - K1; _ld = K2; }        \
        const float* _wp = _Wr + (size_t)(o0 + n) * _ld + _kk + 4 * g;         \
        w0##SUF = *(const float4*)_wp;  w1##SUF = *(const float4*)(_wp + 16);  \
        const float* _xp = _Xb + (size_t)n * _ld + _kk + 4 * g;                \
        x0##SUF = *(const float4*)_xp;  x1##SUF = *(const float4*)(_xp + 16);  \
        const float* _yp = _Xb + (size_t)(16 + n) * _ld + _kk + 4 * g;         \
        y0##SUF = *(const float4*)_yp;  y1##SUF = *(const float4*)(_yp + 16);  \
    }

#define GCONS(SUF)                                                             \
    {                                                                          \
        union { bf16x8 v; uint32_t u4[4]; } wf;                                \
        wf.u4[0] = pkbf(w0##SUF.x, w0##SUF.y);                                 \
        wf.u4[1] = pkbf(w0##SUF.z, w0##SUF.w);                                 \
        wf.u4[2] = pkbf(w1##SUF.x, w1##SUF.y);                                 \
        wf.u4[3] = pkbf(w1##SUF.z, w1##SUF.w);                                 \
        float r0, r1, r2, r3, r4, r5, r6, r7;                                  \
        union { bf16x8 v; uint32_t u4[4]; } xh, xl;                            \
        xh.u4[0] = pk_hi(x0##SUF.x, x0##SUF.y, r0, r1);                        \
        xh.u4[1] = pk_hi(x0##SUF.z, x0##SUF.w, r2, r3);                        \
        xh.u4[2] = pk_hi(x1##SUF.x, x1##SUF.y, r4, r5);                        \
        xh.u4[3] = pk_hi(x1##SUF.z, x1##SUF.w, r6, r7);                        \
        xl.u4[0] = pkbf(r0, r1); xl.u4[1] = pkbf(r2, r3);                      \
        xl.u4[2] = pkbf(r4, r5); xl.u4[3] = pkbf(r6, r7);                      \
        accA = MFMA16(xh.v, wf.v, accA);                                       \
        accA = MFMA16(xl.v, wf.v, accA);                                       \
        xh.u4[0] = pk_hi(y0##SUF.x, y0##SUF.y, r0, r1);                        \
        xh.u4[1] = pk_hi(y0##SUF.z, y0##SUF.w, r2, r3);                        \
        xh.u4[2] = pk_hi(y1##SUF.x, y1##SUF.y, r4, r5);                        \
        xh.u4[3] = pk_hi(y1##SUF.z, y1##SUF.w, r6, r7);                        \
        xl.u4[0] = pkbf(r0, r1); xl.u4[1] = pkbf(r2, r3);                      \
        xl.u4[2] = pkbf(r4, r5); xl.u4[3] = pkbf(r6, r7);                      \
        accB = MFMA16(xh.v, wf.v, accB);                                       \
        accB = MFMA16(xl.v, wf.v, accB);                                       \
    }

__global__ __launch_bounds__(256) void gemm32_mfma(
    const float* __restrict__ X1, const float* __restrict__ W1, int K1,
    const float* __restrict__ X2, const float* __restrict__ W2, int K2,
    float* __restrict__ partial, int O, int ksplit)
{
    const int t  = threadIdx.x;
    const int l  = t & 63;
    const int g  = l >> 4;
    const int n  = l & 15;
    const int o0 = blockIdx.x * 64 + (t >> 6) * 16;   // this wave's o-base
    const int s  = blockIdx.y;
    const int kchunk = (K1 + K2) / ksplit;            // % 64 == 0
    const int kbeg   = s * kchunk;
    const int kend   = kbeg + kchunk;

    f32x4 accA, accB;                 // b rows 0-15 / 16-31
#pragma unroll
    for (int r = 0; r < 4; ++r) { accA[r] = 0.f; accB[r] = 0.f; }

    float4 w0A, w1A, x0A, x1A, y0A, y1A;   // pipeline buffer A
    float4 w0B, w1B, x0B, x1B, y0B, y1B;   // pipeline buffer B

    GLOAD(A, kbeg);
    for (int kc = kbeg; kc < kend; kc += 64) {
        GLOAD(B, kc + 32);                       // in flight during A's consume
        GCONS(A);
        if (kc + 64 < kend) GLOAD(A, kc + 64);   // in flight during B's consume
        GCONS(B);
    }

    // ---- store: b = 16*bh + 4g + r, o = o0 + n
#pragma unroll
    for (int r = 0; r < 4; ++r) {
        partial[((size_t)s * 32 + (4 * g + r)) * O + o0 + n]      = accA[r];
        partial[((size_t)s * 32 + (16 + 4 * g + r)) * O + o0 + n] = accB[r];
    }
}

// ---------------------------------------------------------------------------
// MFMA conv chain (R8/R9 version — unchanged).
// ---------------------------------------------------------------------------
#define TPW 16   // pixel tiles (16 px) per wave

__global__ __launch_bounds__(256, 3) void conv_mfma(
    const float* __restrict__ x, const float* __restrict__ ks,
    float* __restrict__ out)
{
    const int t  = threadIdx.x;
    const int b  = blockIdx.y;
    const int l  = t & 63;
    const int g  = l >> 4;         // lane group 0..3
    const int n  = l & 15;         // col (pixel-in-tile) / A row offset
    const int wid = blockIdx.x * 4 + (t >> 6);   // wave id in sample, 0..63

    const float* __restrict__ kb = ks + (size_t)b * KT;
    const float* __restrict__ xbase = x + (size_t)b * 524288 + (size_t)(4 * g) * 16384 + n;
    float* __restrict__ obase = out + (size_t)b * 524288 + (size_t)(4 * g) * 16384 + n;

    float e[8];
    auto loadx = [&](int px0) {
        const float* p = xbase + px0;
        e[0] = p[0]; e[1] = p[16384]; e[2] = p[2 * 16384]; e[3] = p[3 * 16384];
        const float* q = p + (size_t)16 * 16384;
        e[4] = q[0]; e[5] = q[16384]; e[6] = q[2 * 16384]; e[7] = q[3 * 16384];
    };
    loadx(wid * TPW * 16);

    auto loadA = [&](const float* W, int ldw, int row0, int k0) -> bf16x8 {
        const float* p = W + (size_t)(row0 + n) * ldw + k0 + 4 * g;
        float4 lo = *(const float4*)p;
        float4 hi = *(const float4*)(p + 16);
        union { bf16x8 v; uint32_t u[4]; } r;
        r.u[0] = pkbf(lo.x, lo.y);
        r.u[1] = pkbf(lo.z, lo.w);
        r.u[2] = pkbf(hi.x, hi.y);
        r.u[3] = pkbf(hi.z, hi.w);
        return r.v;
    };
    auto loadBias = [&](int off) -> f32x4 {
        float4 v = *(const float4*)&kb[off + 4 * g];
        f32x4 r; r[0] = v.x; r[1] = v.y; r[2] = v.z; r[3] = v.w;
        return r;
    };

    bf16x8 ain[4], amid[4][2], aout[2][2], ashort[2];
#pragma unroll
    for (int rt = 0; rt < 4; ++rt) ain[rt] = loadA(kb, 32, 16 * rt, 0);
#pragma unroll
    for (int ot = 0; ot < 4; ++ot)
#pragma unroll
        for (int kf = 0; kf < 2; ++kf) amid[ot][kf] = loadA(kb + 2048, 64, 16 * ot, 32 * kf);
#pragma unroll
    for (int ot = 0; ot < 2; ++ot)
#pragma unroll
        for (int kf = 0; kf < 2; ++kf) aout[ot][kf] = loadA(kb + 6144, 64, 16 * ot, 32 * kf);
#pragma unroll
    for (int ot = 0; ot < 2; ++ot) ashort[ot] = loadA(kb + 8192, 32, 16 * ot, 0);

    f32x4 bin[4], bmid[4], bos[2];
#pragma unroll
    for (int rt = 0; rt < 4; ++rt) bin[rt] = loadBias(9216 + 16 * rt);
#pragma unroll
    for (int ot = 0; ot < 4; ++ot) bmid[ot] = loadBias(9280 + 16 * ot);
#pragma unroll
    for (int ot = 0; ot < 2; ++ot) {
        f32x4 a = loadBias(9344 + 16 * ot);   // b_out
        f32x4 c = loadBias(9376 + 16 * ot);   // b_short
#pragma unroll
        for (int r = 0; r < 4; ++r) a[r] += c[r];
        bos[ot] = a;
    }

#pragma unroll 1
    for (int it = 0; it < TPW; ++it) {
        const int px0 = (wid * TPW + it) * 16;

        union { bf16x8 v; uint32_t u[4]; } bx;
        bx.u[0] = pkbf(e[0], e[1]); bx.u[1] = pkbf(e[2], e[3]);
        bx.u[2] = pkbf(e[4], e[5]); bx.u[3] = pkbf(e[6], e[7]);

        if (it + 1 < TPW) loadx(px0 + 16);   // flies under the MFMA chain

        f32x4 h[4];
#pragma unroll
        for (int rt = 0; rt < 4; ++rt) {
            f32x4 acc = MFMA16(ain[rt], bx.v, bin[rt]);
#pragma unroll
            for (int r = 0; r < 4; ++r) acc[r] = fmaxf(acc[r], 0.f);
            h[rt] = acc;
        }
        union { bf16x8 v; uint32_t u[4]; } hb0, hb1;
        hb0.u[0] = pkbf(h[0][0], h[0][1]); hb0.u[1] = pkbf(h[0][2], h[0][3]);
        hb0.u[2] = pkbf(h[1][0], h[1][1]); hb0.u[3] = pkbf(h[1][2], h[1][3]);
        hb1.u[0] = pkbf(h[2][0], h[2][1]); hb1.u[1] = pkbf(h[2][2], h[2][3]);
        hb1.u[2] = pkbf(h[3][0], h[3][1]); hb1.u[3] = pkbf(h[3][2], h[3][3]);

        f32x4 m[4];
#pragma unroll
        for (int ot = 0; ot < 4; ++ot) {
            f32x4 acc = MFMA16(amid[ot][0], hb0.v, bmid[ot]);
            acc = MFMA16(amid[ot][1], hb1.v, acc);
#pragma unroll
            for (int r = 0; r < 4; ++r) acc[r] = fmaxf(acc[r], 0.f);
            m[ot] = acc;
        }
        union { bf16x8 v; uint32_t u[4]; } mb0, mb1;
        mb0.u[0] = pkbf(m[0][0], m[0][1]); mb0.u[1] = pkbf(m[0][2], m[0][3]);
        mb0.u[2] = pkbf(m[1][0], m[1][1]); mb0.u[3] = pkbf(m[1][2], m[1][3]);
        mb1.u[0] = pkbf(m[2][0], m[2][1]); mb1.u[1] = pkbf(m[2][2], m[2][3]);
        mb1.u[2] = pkbf(m[3][0], m[3][1]); mb1.u[3] = pkbf(m[3][2], m[3][3]);

#pragma unroll
        for (int ot = 0; ot < 2; ++ot) {
            f32x4 acc = MFMA16(ashort[ot], bx.v, bos[ot]);
            acc = MFMA16(aout[ot][0], mb0.v, acc);
            acc = MFMA16(aout[ot][1], mb1.v, acc);
            float* po = obase + (size_t)(16 * ot) * 16384 + px0;
            po[0]         = acc[0];
            po[16384]     = acc[1];
            po[2 * 16384] = acc[2];
            po[3 * 16384] = acc[3];
        }
    }
}

// ---------------------------------------------------------------------------
extern "C" void kernel_launch(void* const* d_in, const int* in_sizes, int n_in,
                              void* d_out, int out_size, void* d_ws, size_t ws_size,
                              hipStream_t stream)
{
    const float* x   = (const float*)d_in[0];
    const float* lat = (const float*)d_in[1];
    const float* w0  = (const float*)d_in[2];
    const float* b0  = (const float*)d_in[3];
    const float* w1a = (const float*)d_in[4];
    const float* b1a = (const float*)d_in[5];
    const float* w1b = (const float*)d_in[6];
    const float* b1b = (const float*)d_in[7];
    const float* w1s = (const float*)d_in[8];
    const float* b1s = (const float*)d_in[9];
    const float* w2a = (const float*)d_in[10];
    const float* b2a = (const float*)d_in[11];
    const float* w2b = (const float*)d_in[12];
    const float* b2b = (const float*)d_in[13];
    const float* w2s = (const float*)d_in[14];
    const float* b2s = (const float*)d_in[15];
    const float* wfa = (const float*)d_in[16];
    const float* bfa = (const float*)d_in[17];

    // intermediates in d_ws (~2.8 MB)
    float* ws  = (float*)d_ws;
    float* h0  = ws;               // 32*512
    float* t1  = ws + 16384;       // 32*1024
    float* h1  = ws + 49152;       // 32*512
    float* t2  = ws + 65536;       // 32*1024
    float* h2  = ws + 98304;       // 32*9408
    float* ksb = ws + 399360;      // 32*9408
    // K-split partials live in d_out (<=8.4 MB < 64 MB); conv overwrites at end.
    float* pbuf = (float*)d_out;

    dim3 blk(256);
    auto rg = [](int O) { return dim3((unsigned)((32 * O + 255) / 256)); };

    // small chain (f32, R5-exact)
    gemm32_partial<<<dim3(2, 32), blk, 0, stream>>>(lat, w0, 512, nullptr, nullptr, 0, pbuf, 512, 32);
    reduce_bias<<<rg(512), blk, 0, stream>>>(pbuf, b0, nullptr, h0, 512, 0, 32);
    gemm32_partial<<<dim3(4, 32), blk, 0, stream>>>(h0, w1a, 512, nullptr, nullptr, 0, pbuf, 1024, 32);
    reduce_bias<<<rg(1024), blk, 0, stream>>>(pbuf, b1a, nullptr, t1, 1024, 1, 32);
    gemm32_partial<<<dim3(2, 32), blk, 0, stream>>>(h0, w1s, 512, t1, w1b, 1024, pbuf, 512, 32);
    reduce_bias<<<rg(512), blk, 0, stream>>>(pbuf, b1s, b1b, h1, 512, 0, 32);
    gemm32_partial<<<dim3(4, 32), blk, 0, stream>>>(h1, w2a, 512, nullptr, nullptr, 0, pbuf, 1024, 32);
    reduce_bias<<<rg(1024), blk, 0, stream>>>(pbuf, b2a, nullptr, t2, 1024, 1, 32);

    // h2 = h1 @ w2s.T + b2s + t2 @ w2b.T + b2b   (MFMA, ksplit 6 -> kchunk 256)
    gemm32_mfma<<<dim3(147, 6), blk, 0, stream>>>(h1, w2s, 512, t2, w2b, 1024, pbuf, KT, 6);
    reduce_bias<<<rg(KT), blk, 0, stream>>>(pbuf, b2s, b2b, h2, KT, 0, 6);
    // ks = h2 @ wfa.T + bfa                      (MFMA, ksplit 7 -> kchunk 1344)
    gemm32_mfma<<<dim3(147, 7), blk, 0, stream>>>(h2, wfa, KT, nullptr, nullptr, 0, pbuf, KT, 7);
    reduce_bias<<<rg(KT), blk, 0, stream>>>(pbuf, bfa, nullptr, ksb, KT, 0, 7);

    // MFMA conv chain: grid (16 px-blocks, 32 samples), 4 waves/block, 16 tiles/wave
    conv_mfma<<<dim3(16, 32), blk, 0, stream>>>(x, ksb, (float*)d_out);
}